// Round 1
// baseline (431.715 us; speedup 1.0000x reference)
//
#include <hip/hip_runtime.h>
#include <cstdint>

// Problem constants (fixed by reference): B=2, H=32, S=4096, D=128, BLOCK=512
#define NH 32
#define SEQ 4096
#define DDIM 128
#define BSZ 512
#define SKC 64            // token chunk per staging pass
#define NCH 8             // 512 / 64
#define KT_STRIDE 33      // dwords per row of kT/vT (32 data + 1 pad -> bank-uniform)
#define ST_STRIDE 68      // dwords per row of sT/qs (64 data + 4 pad -> 16B-aligned, bank-uniform b128)
#define OFF_KT 0
#define OFF_VT (128 * KT_STRIDE)                // 4224
#define OFF_ST 0                                // aliases kT/vT region (phase 2 only)
#define OFF_QS (128 * ST_STRIDE)                // 8704
#define OFF_Z  (OFF_QS + SKC * ST_STRIDE)       // 13056  (128 floats)
#define OFF_DEN (OFF_Z + 128)                   // 13184  (64 floats)
#define LDS_DW (OFF_DEN + 64)                   // 13248 dwords = 52992 B

typedef _Float16 f16x8 __attribute__((ext_vector_type(8)));
typedef float f32x4 __attribute__((ext_vector_type(4)));

union FragU { uint32_t u[4]; f16x8 v; };

__device__ __forceinline__ float phi_fn(float x, float s, float b) {
    float y = fmaf(x, s, b);
    return y > 0.0f ? (y + 1.0f) : __expf(y);   // elu(y)+1
}

__device__ __forceinline__ uint32_t pack_f16(float a, float b) {
    union { _Float16 h[2]; uint32_t u; } p;
    p.h[0] = (_Float16)a;
    p.h[1] = (_Float16)b;
    return p.u;
}

__global__ __launch_bounds__(256, 2) void linattn_kernel(
    const float* __restrict__ qg, const float* __restrict__ kg,
    const float* __restrict__ vg, const float* __restrict__ psg,
    const float* __restrict__ pbg, float* __restrict__ outg)
{
    __shared__ uint32_t lds[LDS_DW];
    float*    ldsf = (float*)lds;
    _Float16* ldsh = (_Float16*)lds;

    const int tid  = threadIdx.x;
    const int lane = tid & 63;
    const int wv   = tid >> 6;
    const int l15  = lane & 15;
    const int qd   = lane >> 4;

    const int gid = blockIdx.x;          // 512 = B*H*nb
    const int nb  = gid & 7;
    const int hh  = (gid >> 3) & 31;
    const int bb  = gid >> 8;

    const size_t base = ((size_t)(bb * NH + hh) * SEQ + (size_t)nb * BSZ) * DDIM;

    // Phase-1 staging assignment: thread -> fixed feature dim d1, token half
    const int d1 = tid & 127;
    const int hf = tid >> 7;
    const float sc1 = psg[hh * DDIM + d1];
    const float bi1 = pbg[hh * DDIM + d1];

    // Phase-2 staging assignment: thread -> 4 feature dims d4..d4+3
    const int d4 = (tid & 31) * 4;
    const float4 sc4 = *(const float4*)(psg + hh * DDIM + d4);
    const float4 bi4 = *(const float4*)(pbg + hh * DDIM + d4);

    if (tid < 128) ldsf[OFF_Z + tid] = 0.0f;

    float zacc = 0.0f;

    // S^T accumulators: wave wv owns m-rows [wv*32, wv*32+32): 2 m-tiles x 8 d-tiles
    f32x4 acc[2][8];
    #pragma unroll
    for (int a = 0; a < 2; ++a)
        #pragma unroll
        for (int c = 0; c < 8; ++c)
            acc[a][c] = (f32x4){0.f, 0.f, 0.f, 0.f};

    // ---------------- Phase 1: S^T = V^T * phi_K, Z = colsum(phi_K) ----------------
    for (int ch = 0; ch < NCH; ++ch) {
        __syncthreads();   // previous chunk's MFMA reads done before overwrite
        const float* kp = kg + base + (size_t)(ch * SKC) * DDIM + d1;
        const float* vp = vg + base + (size_t)(ch * SKC) * DDIM + d1;
        const int rowk = OFF_KT + d1 * KT_STRIDE + hf * 16;
        const int rowv = OFF_VT + d1 * KT_STRIDE + hf * 16;
        #pragma unroll 4
        for (int i = 0; i < 16; ++i) {
            const int sl = hf * 32 + 2 * i;
            float k0 = kp[(size_t)sl * DDIM];
            float k1 = kp[(size_t)(sl + 1) * DDIM];
            float v0 = vp[(size_t)sl * DDIM];
            float v1 = vp[(size_t)(sl + 1) * DDIM];
            float p0 = phi_fn(k0, sc1, bi1);
            float p1 = phi_fn(k1, sc1, bi1);
            zacc += p0 + p1;
            lds[rowk + i] = pack_f16(p0, p1);   // kT[d][s] transposed, pair-packed
            lds[rowv + i] = pack_f16(v0, v1);   // vT[m][s]
        }
        __syncthreads();
        #pragma unroll
        for (int ks = 0; ks < 2; ++ks) {        // K=32 tokens per MFMA step
            FragU af[2];
            #pragma unroll
            for (int tm = 0; tm < 2; ++tm) {
                const int m  = wv * 32 + tm * 16 + l15;
                const int ad = OFF_VT + m * KT_STRIDE + ks * 16 + qd * 4;
                af[tm].u[0] = lds[ad + 0]; af[tm].u[1] = lds[ad + 1];
                af[tm].u[2] = lds[ad + 2]; af[tm].u[3] = lds[ad + 3];
            }
            #pragma unroll
            for (int td = 0; td < 8; ++td) {
                const int dd = td * 16 + l15;
                const int bd = OFF_KT + dd * KT_STRIDE + ks * 16 + qd * 4;
                FragU bf;
                bf.u[0] = lds[bd + 0]; bf.u[1] = lds[bd + 1];
                bf.u[2] = lds[bd + 2]; bf.u[3] = lds[bd + 3];
                acc[0][td] = __builtin_amdgcn_mfma_f32_16x16x32_f16(af[0].v, bf.v, acc[0][td], 0, 0, 0);
                acc[1][td] = __builtin_amdgcn_mfma_f32_16x16x32_f16(af[1].v, bf.v, acc[1][td], 0, 0, 0);
            }
        }
    }

    atomicAdd(&ldsf[OFF_Z + d1], zacc);
    __syncthreads();   // Z complete; all kT/vT reads complete before sT overwrite

    // Spill S^T (fp16) to LDS: C/D layout row = qd*4+r, col = l15
    #pragma unroll
    for (int tm = 0; tm < 2; ++tm)
        #pragma unroll
        for (int td = 0; td < 8; ++td)
            #pragma unroll
            for (int r = 0; r < 4; ++r) {
                const int m  = wv * 32 + tm * 16 + qd * 4 + r;
                const int dd = td * 16 + l15;
                ldsh[m * (ST_STRIDE * 2) + dd] = (_Float16)acc[tm][td][r];
            }

    const float4 zq = *(const float4*)(ldsf + OFF_Z + d4);  // after Z barrier

    // ---------------- Phase 2: num = phi_Q * S, den = phi_Q . Z ----------------
    const int sl2 = tid >> 5;
    for (int qc = 0; qc < 8; ++qc) {
        __syncthreads();   // previous chunk's qs/den reads done; sT writes visible before first MFMA
        const float* qp = qg + base + (size_t)(qc * SKC) * DDIM + d4;
        #pragma unroll 2
        for (int i = 0; i < 8; ++i) {
            const int srow = sl2 + i * 8;
            const float4 qv = *(const float4*)(qp + (size_t)srow * DDIM);
            float p0 = phi_fn(qv.x, sc4.x, bi4.x);
            float p1 = phi_fn(qv.y, sc4.y, bi4.y);
            float p2 = phi_fn(qv.z, sc4.z, bi4.z);
            float p3 = phi_fn(qv.w, sc4.w, bi4.w);
            const int ad = OFF_QS + srow * ST_STRIDE + (tid & 31) * 2;
            lds[ad + 0] = pack_f16(p0, p1);
            lds[ad + 1] = pack_f16(p2, p3);
            // den[srow]: 32 lanes cover all 128 dims -> shuffle-reduce, no atomics
            float pd = p0 * zq.x + p1 * zq.y + p2 * zq.z + p3 * zq.w;
            pd += __shfl_xor(pd, 16);
            pd += __shfl_xor(pd, 8);
            pd += __shfl_xor(pd, 4);
            pd += __shfl_xor(pd, 2);
            pd += __shfl_xor(pd, 1);
            if ((tid & 31) == 0) ldsf[OFF_DEN + srow] = pd;
        }
        __syncthreads();

        f32x4 acc2[8];
        #pragma unroll
        for (int c = 0; c < 8; ++c) acc2[c] = (f32x4){0.f, 0.f, 0.f, 0.f};

        #pragma unroll
        for (int ks = 0; ks < 4; ++ks) {        // K=32 dims per MFMA step
            const int srow = wv * 16 + l15;
            const int ad = OFF_QS + srow * ST_STRIDE + ks * 16 + qd * 4;
            FragU af;
            const uint4 t0 = *(const uint4*)(lds + ad);   // 16B-aligned ds_read_b128
            af.u[0] = t0.x; af.u[1] = t0.y; af.u[2] = t0.z; af.u[3] = t0.w;
            #pragma unroll
            for (int tn = 0; tn < 8; ++tn) {
                const int mm = tn * 16 + l15;
                const int bd = OFF_ST + mm * ST_STRIDE + ks * 16 + qd * 4;
                const uint4 t1 = *(const uint4*)(lds + bd);
                FragU bf;
                bf.u[0] = t1.x; bf.u[1] = t1.y; bf.u[2] = t1.z; bf.u[3] = t1.w;
                acc2[tn] = __builtin_amdgcn_mfma_f32_16x16x32_f16(af.v, bf.v, acc2[tn], 0, 0, 0);
            }
        }

        // Epilogue: out = num / (den + eps)
        #pragma unroll
        for (int r = 0; r < 4; ++r) {
            const int srow = wv * 16 + qd * 4 + r;
            const float rden = 1.0f / (ldsf[OFF_DEN + srow] + 1e-6f);
            float* op = outg + base + (size_t)(qc * SKC + srow) * DDIM;
            #pragma unroll
            for (int tn = 0; tn < 8; ++tn)
                op[tn * 16 + l15] = acc2[tn][r] * rden;
        }
    }
}

extern "C" void kernel_launch(void* const* d_in, const int* in_sizes, int n_in,
                              void* d_out, int out_size, void* d_ws, size_t ws_size,
                              hipStream_t stream) {
    const float* q  = (const float*)d_in[0];
    const float* k  = (const float*)d_in[1];
    const float* v  = (const float*)d_in[2];
    const float* ps = (const float*)d_in[3];
    const float* pb = (const float*)d_in[4];
    float* out = (float*)d_out;
    // grid = B*H*nb = 2*32*8 = 512 workgroups, 256 threads (4 waves) each
    linattn_kernel<<<dim3(512), dim3(256), 0, stream>>>(q, k, v, ps, pb, out);
}

// Round 2
// 405.351 us; speedup vs baseline: 1.0650x; 1.0650x over previous
//
#include <hip/hip_runtime.h>
#include <cstdint>

// Problem constants (fixed by reference): B=2, H=32, S=4096, D=128, BLOCK=512
#define NH 32
#define SEQ 4096
#define DDIM 128
#define BSZ 512
#define SKC 64            // token chunk per staging pass
#define NCH 8             // 512 / 64
#define KT_STRIDE 33      // dwords per row of kT/vT (32 data + 1 pad -> 2-way banks = free)
#define ST_STRIDE 68      // dwords per row of sT/qs (64 data + 4 pad -> 16B-aligned b128)
// Phase-1 double buffers (each 128 rows x KT_STRIDE dwords = 4224 dw)
#define OFF_K0 0
#define OFF_V0 (128 * KT_STRIDE)                // 4224
#define OFF_K1 (2 * 128 * KT_STRIDE)            // 8448
#define OFF_V1 (3 * 128 * KT_STRIDE)            // 12672, end 16896
// Phase-2 (aliases phase-1 region; separated by barriers)
#define OFF_ST 0                                // 128 x 68 = 8704 dw
#define OFF_QS0 (128 * ST_STRIDE)               // 8704, 64 x 68 = 4352 dw
#define OFF_QS1 (OFF_QS0 + 64 * ST_STRIDE)      // 13056, end 17408
#define OFF_Z   (OFF_QS1 + 64 * ST_STRIDE)      // 17408 (128 floats, no alias)
#define OFF_DEN0 (OFF_Z + 128)                  // 17536 (64 floats)
#define OFF_DEN1 (OFF_DEN0 + 64)                // 17600
#define LDS_DW (OFF_DEN1 + 64)                  // 17664 dw = 70656 B -> 2 blocks/CU

typedef _Float16 f16x8 __attribute__((ext_vector_type(8)));
typedef float f32x4 __attribute__((ext_vector_type(4)));

union FragU { uint32_t u[4]; f16x8 v; };

__device__ __forceinline__ float phi_fn(float x, float s, float b) {
    float y = fmaf(x, s, b);
    return y > 0.0f ? (y + 1.0f) : __expf(y);   // elu(y)+1
}

__device__ __forceinline__ uint32_t pack_f16(float a, float b) {
    union { _Float16 h[2]; uint32_t u; } p;
    p.h[0] = (_Float16)a;
    p.h[1] = (_Float16)b;
    return p.u;
}

__global__ __launch_bounds__(256, 2) void linattn_kernel(
    const float* __restrict__ qg, const float* __restrict__ kg,
    const float* __restrict__ vg, const float* __restrict__ psg,
    const float* __restrict__ pbg, float* __restrict__ outg)
{
    __shared__ uint32_t lds[LDS_DW];
    float*    ldsf = (float*)lds;
    _Float16* ldsh = (_Float16*)lds;

    const int tid  = threadIdx.x;
    const int lane = tid & 63;
    const int wv   = tid >> 6;
    const int l15  = lane & 15;
    const int qd   = lane >> 4;

    const int gid = blockIdx.x;          // 512 = B*H*nb
    const int nb  = gid & 7;
    const int hh  = (gid >> 3) & 31;
    const int bb  = gid >> 8;

    const size_t base = ((size_t)(bb * NH + hh) * SEQ + (size_t)nb * BSZ) * DDIM;

    // Phase-1 staging: thread owns dim-pair (2*dp, 2*dp+1), token quarter qt
    const int dp = tid & 63;
    const int qt = tid >> 6;             // == wave id -> wave-uniform token quarter
    const float2 sc2 = *(const float2*)(psg + hh * DDIM + 2 * dp);
    const float2 bi2 = *(const float2*)(pbg + hh * DDIM + 2 * dp);

    // Phase-2 staging: thread owns 4 feature dims d4..d4+3
    const int d4  = (tid & 31) * 4;
    const int sl2 = tid >> 5;
    const float4 sc4 = *(const float4*)(psg + hh * DDIM + d4);
    const float4 bi4 = *(const float4*)(pbg + hh * DDIM + d4);

    if (tid < 128) ldsf[OFF_Z + tid] = 0.0f;

    float z0 = 0.0f, z1 = 0.0f;

    // S^T accumulators: wave wv owns m-rows [wv*32, wv*32+32): 2 m-tiles x 8 d-tiles
    f32x4 acc[2][8];
    #pragma unroll
    for (int a = 0; a < 2; ++a)
        #pragma unroll
        for (int c = 0; c < 8; ++c)
            acc[a][c] = (f32x4){0.f, 0.f, 0.f, 0.f};

    // ---------------- Phase 1: S^T = V^T * phi_K, Z = colsum(phi_K) ----------------
    float2 kr[16], vr[16];               // prefetch registers (one chunk)
    const float* kbase = kg + base + 2 * dp;
    const float* vbase = vg + base + 2 * dp;

    auto loadkv = [&](int ch) {
        const size_t off = (size_t)(ch * SKC + qt * 16) * DDIM;
        #pragma unroll
        for (int j = 0; j < 16; ++j) {
            kr[j] = *(const float2*)(kbase + off + (size_t)j * DDIM);
            vr[j] = *(const float2*)(vbase + off + (size_t)j * DDIM);
        }
    };
    auto stagekv = [&](int buf) {        // stage regs -> LDS buf, transposed + phi
        uint32_t* bk = lds + (buf ? OFF_K1 : OFF_K0) + qt * 8;
        uint32_t* bv = lds + (buf ? OFF_V1 : OFF_V0) + qt * 8;
        const int r0 = (2 * dp) * KT_STRIDE;
        const int r1 = r0 + KT_STRIDE;
        #pragma unroll
        for (int j = 0; j < 8; ++j) {
            float p0x = phi_fn(kr[2*j].x,   sc2.x, bi2.x);
            float p1x = phi_fn(kr[2*j+1].x, sc2.x, bi2.x);
            float p0y = phi_fn(kr[2*j].y,   sc2.y, bi2.y);
            float p1y = phi_fn(kr[2*j+1].y, sc2.y, bi2.y);
            z0 += p0x + p1x;
            z1 += p0y + p1y;
            bk[r0 + j] = pack_f16(p0x, p1x);
            bk[r1 + j] = pack_f16(p0y, p1y);
            bv[r0 + j] = pack_f16(vr[2*j].x, vr[2*j+1].x);
            bv[r1 + j] = pack_f16(vr[2*j].y, vr[2*j+1].y);
        }
    };
    auto mfma1 = [&](int buf) {
        const int offK = buf ? OFF_K1 : OFF_K0;
        const int offV = buf ? OFF_V1 : OFF_V0;
        #pragma unroll
        for (int ks = 0; ks < 2; ++ks) {     // K=32 tokens per MFMA step
            FragU af[2];
            #pragma unroll
            for (int tm = 0; tm < 2; ++tm) {
                const int m  = wv * 32 + tm * 16 + l15;
                const int ad = offV + m * KT_STRIDE + ks * 16 + qd * 4;
                af[tm].u[0] = lds[ad + 0]; af[tm].u[1] = lds[ad + 1];
                af[tm].u[2] = lds[ad + 2]; af[tm].u[3] = lds[ad + 3];
            }
            #pragma unroll
            for (int td = 0; td < 8; ++td) {
                const int dd = td * 16 + l15;
                const int bd = offK + dd * KT_STRIDE + ks * 16 + qd * 4;
                FragU bf;
                bf.u[0] = lds[bd + 0]; bf.u[1] = lds[bd + 1];
                bf.u[2] = lds[bd + 2]; bf.u[3] = lds[bd + 3];
                acc[0][td] = __builtin_amdgcn_mfma_f32_16x16x32_f16(af[0].v, bf.v, acc[0][td], 0, 0, 0);
                acc[1][td] = __builtin_amdgcn_mfma_f32_16x16x32_f16(af[1].v, bf.v, acc[1][td], 0, 0, 0);
            }
        }
    };

    loadkv(0);
    stagekv(0);          // chunk 0 -> buf0 (waits its loads)
    loadkv(1);
    __syncthreads();
    for (int ch = 0; ch < NCH; ++ch) {
        // stage ch+1 (regs already loaded) into the buffer MFMA(ch) is NOT reading
        if (ch + 1 < NCH) stagekv((ch + 1) & 1);
        // prefetch ch+2 while MFMA(ch) runs
        if (ch + 2 < NCH) loadkv(ch + 2);
        mfma1(ch & 1);
        __syncthreads();  // staging(ch+1) visible; buf(ch&1) free for staging(ch+2)
    }

    atomicAdd(&ldsf[OFF_Z + 2 * dp],     z0);
    atomicAdd(&ldsf[OFF_Z + 2 * dp + 1], z1);

    // Spill S^T (fp16) to LDS: C/D layout row = qd*4+r, col = l15
    #pragma unroll
    for (int tm = 0; tm < 2; ++tm)
        #pragma unroll
        for (int td = 0; td < 8; ++td)
            #pragma unroll
            for (int r = 0; r < 4; ++r) {
                const int m  = wv * 32 + tm * 16 + qd * 4 + r;
                const int dd = td * 16 + l15;
                ldsh[m * (ST_STRIDE * 2) + dd] = (_Float16)acc[tm][td][r];
            }
    __syncthreads();     // sT + Z complete

    const float4 zq = *(const float4*)(ldsf + OFF_Z + d4);

    // ---------------- Phase 2: num = phi_Q * S, den = phi_Q . Z ----------------
    float4 qr[8];        // prefetch registers (one q-chunk)
    const float* qbase = qg + base + d4;

    auto loadq = [&](int qc) {
        const size_t off = (size_t)(qc * SKC) * DDIM;
        #pragma unroll
        for (int i = 0; i < 8; ++i)
            qr[i] = *(const float4*)(qbase + off + (size_t)(sl2 + i * 8) * DDIM);
    };
    auto stageq = [&](int buf) {
        uint32_t* qsb  = lds  + (buf ? OFF_QS1  : OFF_QS0);
        float*    denb = ldsf + (buf ? OFF_DEN1 : OFF_DEN0);
        #pragma unroll
        for (int i = 0; i < 8; ++i) {
            const int srow = sl2 + i * 8;
            float p0 = phi_fn(qr[i].x, sc4.x, bi4.x);
            float p1 = phi_fn(qr[i].y, sc4.y, bi4.y);
            float p2 = phi_fn(qr[i].z, sc4.z, bi4.z);
            float p3 = phi_fn(qr[i].w, sc4.w, bi4.w);
            uint2 w;
            w.x = pack_f16(p0, p1);
            w.y = pack_f16(p2, p3);
            *(uint2*)(qsb + srow * ST_STRIDE + (tid & 31) * 2) = w;
            float pd = p0 * zq.x + p1 * zq.y + p2 * zq.z + p3 * zq.w;
            pd += __shfl_xor(pd, 16);
            pd += __shfl_xor(pd, 8);
            pd += __shfl_xor(pd, 4);
            pd += __shfl_xor(pd, 2);
            pd += __shfl_xor(pd, 1);
            if ((tid & 31) == 0) denb[srow] = pd;
        }
    };

    loadq(0);
    stageq(0);           // q-chunk 0 -> qs0/den0
    loadq(1);
    __syncthreads();

    for (int qc = 0; qc < 8; ++qc) {
        if (qc + 1 < 8) stageq((qc + 1) & 1);
        if (qc + 2 < 8) loadq(qc + 2);

        f32x4 acc2[8];
        #pragma unroll
        for (int c = 0; c < 8; ++c) acc2[c] = (f32x4){0.f, 0.f, 0.f, 0.f};

        const int qsOff  = (qc & 1) ? OFF_QS1  : OFF_QS0;
        const int denOff = (qc & 1) ? OFF_DEN1 : OFF_DEN0;

        #pragma unroll
        for (int ks = 0; ks < 4; ++ks) {     // K=32 dims per MFMA step
            const int srow = wv * 16 + l15;
            const int ad = qsOff + srow * ST_STRIDE + ks * 16 + qd * 4;
            FragU af;
            const uint4 t0 = *(const uint4*)(lds + ad);   // 16B-aligned ds_read_b128
            af.u[0] = t0.x; af.u[1] = t0.y; af.u[2] = t0.z; af.u[3] = t0.w;
            #pragma unroll
            for (int tn = 0; tn < 8; ++tn) {
                const int mm = tn * 16 + l15;
                const uint4 t1 = *(const uint4*)(lds + OFF_ST + mm * ST_STRIDE + ks * 16 + qd * 4);
                FragU bf;
                bf.u[0] = t1.x; bf.u[1] = t1.y; bf.u[2] = t1.z; bf.u[3] = t1.w;
                acc2[tn] = __builtin_amdgcn_mfma_f32_16x16x32_f16(af.v, bf.v, acc2[tn], 0, 0, 0);
            }
        }

        // Epilogue: out = num / (den + eps), non-temporal stores
        #pragma unroll
        for (int r = 0; r < 4; ++r) {
            const int srow = wv * 16 + qd * 4 + r;
            const float rden = 1.0f / (ldsf[denOff + srow] + 1e-6f);
            float* op = outg + base + (size_t)(qc * SKC + srow) * DDIM;
            #pragma unroll
            for (int tn = 0; tn < 8; ++tn)
                __builtin_nontemporal_store(acc2[tn][r] * rden, op + tn * 16 + l15);
        }
        if (qc + 1 < 8) __syncthreads();
    }
}

extern "C" void kernel_launch(void* const* d_in, const int* in_sizes, int n_in,
                              void* d_out, int out_size, void* d_ws, size_t ws_size,
                              hipStream_t stream) {
    const float* q  = (const float*)d_in[0];
    const float* k  = (const float*)d_in[1];
    const float* v  = (const float*)d_in[2];
    const float* ps = (const float*)d_in[3];
    const float* pb = (const float*)d_in[4];
    float* out = (float*)d_out;
    // grid = B*H*nb = 2*32*8 = 512 workgroups, 256 threads (4 waves) each
    linattn_kernel<<<dim3(512), dim3(256), 0, stream>>>(q, k, v, ps, pb, out);
}